// Round 5
// baseline (250.367 us; speedup 1.0000x reference)
//
#include <hip/hip_runtime.h>
#include <hip/hip_bf16.h>

typedef unsigned short u16;
typedef unsigned int u32;
typedef __attribute__((ext_vector_type(4))) float f32x4;
typedef __attribute__((ext_vector_type(8))) short s16x8;
typedef __attribute__((ext_vector_type(4))) unsigned short u16x4;
typedef __attribute__((ext_vector_type(8))) unsigned short u16x8;

#define LRELU(x) ((x) > 0.f ? (x) : 0.01f * (x))

static __device__ __forceinline__ u16 f2bf(float x) {
    u32 u = __float_as_uint(x);
    return (u16)((u + 0x7fffu + ((u >> 16) & 1u)) >> 16);
}
static __device__ __forceinline__ float bf2f(u16 h) { return __uint_as_float((u32)h << 16); }

// ---------------- prep: w1 = W*a1, w2 = W*a2, Wt hi/lo transpose-split -------
__global__ void k_prep(const float* __restrict__ W, const float* __restrict__ a,
                       u16* __restrict__ Wt_hi, u16* __restrict__ Wt_lo,
                       float* __restrict__ w1, float* __restrict__ w2) {
    int i = blockIdx.x, t = threadIdx.x;
    float x = W[i * 256 + t];
    float p1 = x * a[t];
    float p2 = x * a[256 + t];
#pragma unroll
    for (int off = 1; off < 64; off <<= 1) {
        p1 += __shfl_xor(p1, off);
        p2 += __shfl_xor(p2, off);
    }
    __shared__ float s1[4], s2[4];
    if ((t & 63) == 0) { s1[t >> 6] = p1; s2[t >> 6] = p2; }
    __syncthreads();
    if (t == 0) {
        w1[i] = s1[0] + s1[1] + s1[2] + s1[3];
        w2[i] = s2[0] + s2[1] + s2[2] + s2[3];
    }
    float y = W[t * 256 + i];
    u16 hi = f2bf(y);
    Wt_hi[i * 256 + t] = hi;
    Wt_lo[i * 256 + t] = f2bf(y - bf2f(hi));
}

// ---------------- f1/f2: exact fp32 row dots of inp with w1/w2 --------------
__global__ void k_f(const float* __restrict__ inp, const float* __restrict__ w1,
                    const float* __restrict__ w2, float* __restrict__ f1,
                    float* __restrict__ f2) {
    __shared__ float sw1[256], sw2[256];
    int t = threadIdx.x;
    sw1[t] = w1[t];
    sw2[t] = w2[t];
    __syncthreads();
    int wv = t >> 6, l = t & 63;
    f32x4 c1 = *(const f32x4*)&sw1[l * 4];
    f32x4 c2 = *(const f32x4*)&sw2[l * 4];
    for (int it = 0; it < 16; ++it) {
        int row = blockIdx.x * 64 + wv * 16 + it;
        f32x4 v = *(const f32x4*)&inp[row * 256 + l * 4];
        float d1 = v.x * c1.x + v.y * c1.y + v.z * c1.z + v.w * c1.w;
        float d2 = v.x * c2.x + v.y * c2.y + v.z * c2.z + v.w * c2.w;
#pragma unroll
        for (int off = 1; off < 64; off <<= 1) {
            d1 += __shfl_xor(d1, off);
            d2 += __shfl_xor(d2, off);
        }
        if (l == 0) { f1[row] = d1; f2[row] = d2; }
    }
}

// ---------------- per-batch max of f2 ---------------------------------------
__global__ void k_m(const float* __restrict__ f2, float* __restrict__ Mb) {
    int b = blockIdx.x, t = threadIdx.x;
    float m = -1e30f;
#pragma unroll
    for (int j = 0; j < 4; ++j) m = fmaxf(m, f2[b * 1024 + t + j * 256]);
#pragma unroll
    for (int off = 1; off < 64; off <<= 1) m = fmaxf(m, __shfl_xor(m, off));
    __shared__ float s[4];
    if ((t & 63) == 0) s[t >> 6] = m;
    __syncthreads();
    if (t == 0) Mb[b] = fmaxf(fmaxf(s[0], s[1]), fmaxf(s[2], s[3]));
}

// ---------------- k_h: ht = (inp @ W)^T, hi/lo bf16, 3-term split -----------
// Block = 64 n-rows x 256 f (waves split f). inp read exactly once from HBM.
__global__ __launch_bounds__(256, 2) void k_h(const float* __restrict__ inp,
                                              const u16* __restrict__ Wt_hi,
                                              const u16* __restrict__ Wt_lo,
                                              u16* __restrict__ ht_hi,
                                              u16* __restrict__ ht_lo) {
    int t = threadIdx.x, w = t >> 6, l = t & 63, lr = l & 15, lk = l >> 4;
    int n0 = blockIdx.x * 64;
    int bb = n0 >> 10, nb0 = n0 & 1023;

    f32x4 acc[4][4];
#pragma unroll
    for (int i = 0; i < 4; ++i)
#pragma unroll
        for (int j = 0; j < 4; ++j)
#pragma unroll
            for (int r = 0; r < 4; ++r) acc[i][j][r] = 0.f;

    for (int kt = 0; kt < 8; ++kt) {
        int k0 = kt * 32 + lk * 8;
        s16x8 ah[4], al[4];
#pragma unroll
        for (int it = 0; it < 4; ++it) {
            int f = w * 64 + it * 16 + lr;
            ah[it] = *(const s16x8*)&Wt_hi[f * 256 + k0];
            al[it] = *(const s16x8*)&Wt_lo[f * 256 + k0];
        }
        s16x8 bh[4], bl[4];
#pragma unroll
        for (int ci = 0; ci < 4; ++ci) {
            int n = n0 + ci * 16 + lr;
            f32x4 v0 = *(const f32x4*)&inp[n * 256 + k0];
            f32x4 v1 = *(const f32x4*)&inp[n * 256 + k0 + 4];
            u16x8 hv, lv;
#pragma unroll
            for (int j = 0; j < 4; ++j) {
                u16 h0 = f2bf(v0[j]);
                hv[j] = h0;
                lv[j] = f2bf(v0[j] - bf2f(h0));
                u16 h1 = f2bf(v1[j]);
                hv[j + 4] = h1;
                lv[j + 4] = f2bf(v1[j] - bf2f(h1));
            }
            bh[ci] = *(s16x8*)&hv;
            bl[ci] = *(s16x8*)&lv;
        }
#pragma unroll
        for (int it = 0; it < 4; ++it)
#pragma unroll
            for (int ci = 0; ci < 4; ++ci) {
                acc[it][ci] = __builtin_amdgcn_mfma_f32_16x16x32_bf16(ah[it], bh[ci], acc[it][ci], 0, 0, 0);
                acc[it][ci] = __builtin_amdgcn_mfma_f32_16x16x32_bf16(ah[it], bl[ci], acc[it][ci], 0, 0, 0);
                acc[it][ci] = __builtin_amdgcn_mfma_f32_16x16x32_bf16(al[it], bh[ci], acc[it][ci], 0, 0, 0);
            }
    }
#pragma unroll
    for (int it = 0; it < 4; ++it)
#pragma unroll
        for (int ci = 0; ci < 4; ++ci) {
            int col = nb0 + ci * 16 + lr;
#pragma unroll
            for (int r = 0; r < 4; ++r) {
                int F = w * 64 + it * 16 + lk * 4 + r;
                float x = acc[it][ci][r];
                u16 hh = f2bf(x);
                size_t o = (size_t)(bb * 256 + F) * 1024 + col;
                ht_hi[o] = hh;
                ht_lo[o] = f2bf(x - bf2f(hh));
            }
        }
}

// ---------------- attention: softmax(leaky(f1+f2)) @ h, elu -----------------
// 512-thread blocks (8 waves): waves split f 4-ways x rowgroup 2-ways.
// P computed once per row (split rowgroup x j-half across waves), shared via LDS.
__global__ __launch_bounds__(512, 4) void k_attn(const u16* __restrict__ ht_hi,
                                                 const u16* __restrict__ ht_lo,
                                                 const float* __restrict__ f1,
                                                 const float* __restrict__ f2,
                                                 const float* __restrict__ Mb,
                                                 float* __restrict__ out) {
    __shared__ float sf2[1024];
    __shared__ u16 P[2][4][4][512];  // [buf][rowgroup][s][lane*8]
    __shared__ float rs[128];
    int t = threadIdx.x, w = t >> 6, l = t & 63, lr = l & 15, lk = l >> 4;
    int wf = w & 3, wr = w >> 2;
    int g = blockIdx.x;
    int xcd = g & 7, idx = g >> 3;
    int b = xcd * 4 + (idx >> 4);
    int i0 = (idx & 15) * 64;

    if (t < 256) *(f32x4*)&sf2[t * 4] = *(const f32x4*)&f2[b * 1024 + t * 4];
    float Mv = Mb[b];
    int rgp = wf;  // P rowgroup this wave computes
    int sh = wr;   // j-half (s pair) this wave computes
    float f1v = f1[b * 1024 + i0 + rgp * 16 + lr];
    float miv = LRELU(f1v + Mv);
    float lsum = 0.f;
    const u16* Hh = ht_hi + (size_t)b * 262144;
    const u16* Hl = ht_lo + (size_t)b * 262144;

    auto computeP = [&](int cc2, int buf2) {
#pragma unroll
        for (int ss = 0; ss < 2; ++ss) {
            int s = sh * 2 + ss;
            int jb = cc2 * 128 + s * 32 + lk * 8;
            f32x4 fa = *(const f32x4*)&sf2[jb];
            f32x4 fb = *(const f32x4*)&sf2[jb + 4];
            u16x8 pv;
#pragma unroll
            for (int jj = 0; jj < 8; ++jj) {
                float fv = (jj < 4) ? fa[jj] : fb[jj - 4];
                float e = LRELU(f1v + fv);
                float p = __expf(e - miv);
                lsum += p;
                pv[jj] = f2bf(p);
            }
            *(u16x8*)&P[buf2][rgp][s][l * 8] = pv;
        }
    };

    f32x4 acc[2][4];
#pragma unroll
    for (int i = 0; i < 2; ++i)
#pragma unroll
        for (int j = 0; j < 4; ++j)
#pragma unroll
            for (int r = 0; r < 4; ++r) acc[i][j][r] = 0.f;

    __syncthreads();  // sf2 visible
    computeP(0, 0);

    for (int cc = 0; cc < 8; ++cc) {
        __syncthreads();  // P(cc) visible; prev-buf readers done
        if (cc < 7) computeP(cc + 1, (cc + 1) & 1);
        int buf = cc & 1;
#pragma unroll
        for (int s = 0; s < 4; ++s) {
            int jcol = cc * 128 + s * 32 + lk * 8;
            s16x8 pf[2];
            pf[0] = *(const s16x8*)&P[buf][wr * 2][s][l * 8];
            pf[1] = *(const s16x8*)&P[buf][wr * 2 + 1][s][l * 8];
#pragma unroll
            for (int ci = 0; ci < 4; ++ci) {
                int f = wf * 64 + ci * 16 + lr;
                s16x8 bh = *(const s16x8*)&Hh[(size_t)f * 1024 + jcol];
                s16x8 bl = *(const s16x8*)&Hl[(size_t)f * 1024 + jcol];
                __builtin_amdgcn_s_setprio(1);
                acc[0][ci] = __builtin_amdgcn_mfma_f32_16x16x32_bf16(pf[0], bh, acc[0][ci], 0, 0, 0);
                acc[0][ci] = __builtin_amdgcn_mfma_f32_16x16x32_bf16(pf[0], bl, acc[0][ci], 0, 0, 0);
                acc[1][ci] = __builtin_amdgcn_mfma_f32_16x16x32_bf16(pf[1], bh, acc[1][ci], 0, 0, 0);
                acc[1][ci] = __builtin_amdgcn_mfma_f32_16x16x32_bf16(pf[1], bl, acc[1][ci], 0, 0, 0);
                __builtin_amdgcn_s_setprio(0);
            }
        }
    }

    // row sums: reduce lk lanes in-wave, then combine the two j-half waves
    lsum += __shfl_xor(lsum, 16);
    lsum += __shfl_xor(lsum, 32);
    if (l < 16) rs[w * 16 + lr] = lsum;
    __syncthreads();

#pragma unroll
    for (int it = 0; it < 2; ++it) {
        int rg = wr * 2 + it;
        f32x4 s1 = *(const f32x4*)&rs[rg * 16 + lk * 4];
        f32x4 s2 = *(const f32x4*)&rs[(rg + 4) * 16 + lk * 4];
        f32x4 sums = s1 + s2;
#pragma unroll
        for (int ci = 0; ci < 4; ++ci) {
            int col = wf * 64 + ci * 16 + lr;
            int rowg = b * 1024 + i0 + rg * 16 + lk * 4;
#pragma unroll
            for (int r = 0; r < 4; ++r) {
                float v = acc[it][ci][r] / sums[r];
                v = v > 0.f ? v : (__expf(v) - 1.f);
                out[(size_t)(rowg + r) * 256 + col] = v;
            }
        }
    }
}

extern "C" void kernel_launch(void* const* d_in, const int* in_sizes, int n_in,
                              void* d_out, int out_size, void* d_ws, size_t ws_size,
                              hipStream_t stream) {
    const float* inp = (const float*)d_in[0];
    const float* W = (const float*)d_in[1];
    const float* a = (const float*)d_in[2];
    float* out = (float*)d_out;

    char* ws = (char*)d_ws;
    u16* ht_hi = (u16*)(ws + 0);            // 16,777,216 B
    u16* ht_lo = (u16*)(ws + 16777216);     // 16,777,216 B
    u16* Wt_hi = (u16*)(ws + 33554432);     // 131,072 B
    u16* Wt_lo = (u16*)(ws + 33685504);     // 131,072 B
    float* w1 = (float*)(ws + 33816576);    // 1,024 B
    float* w2 = (float*)(ws + 33817600);    // 1,024 B
    float* f1 = (float*)(ws + 33818624);    // 131,072 B
    float* f2 = (float*)(ws + 33949696);    // 131,072 B
    float* Mb = (float*)(ws + 34080768);    // 128 B

    k_prep<<<256, 256, 0, stream>>>(W, a, Wt_hi, Wt_lo, w1, w2);
    k_f<<<512, 256, 0, stream>>>(inp, w1, w2, f1, f2);
    k_m<<<32, 256, 0, stream>>>(f2, Mb);
    k_h<<<512, 256, 0, stream>>>(inp, Wt_hi, Wt_lo, ht_hi, ht_lo);
    k_attn<<<512, 512, 0, stream>>>(ht_hi, ht_lo, f1, f2, Mb, out);
}

// Round 7
// 201.213 us; speedup vs baseline: 1.2443x; 1.2443x over previous
//
#include <hip/hip_runtime.h>
#include <hip/hip_bf16.h>

typedef unsigned short u16;
typedef unsigned int u32;
typedef __attribute__((ext_vector_type(4))) float f32x4;
typedef __attribute__((ext_vector_type(8))) _Float16 f16x8;
typedef __attribute__((ext_vector_type(8))) unsigned short u16x8;

#define LRELU(x) ((x) > 0.f ? (x) : 0.01f * (x))

static __device__ __forceinline__ u16 f2h(float x) {
    _Float16 h = (_Float16)x;
    u16 r;
    __builtin_memcpy(&r, &h, 2);
    return r;
}
static __device__ __forceinline__ float h2f(u16 v) {
    _Float16 h;
    __builtin_memcpy(&h, &v, 2);
    return (float)h;
}

// ---------------- prep: w1 = W*a1, w2 = W*a2, Wt hi/lo fp16 transpose-split --
__global__ void k_prep(const float* __restrict__ W, const float* __restrict__ a,
                       u16* __restrict__ Wt_hi, u16* __restrict__ Wt_lo,
                       float* __restrict__ w1, float* __restrict__ w2) {
    int i = blockIdx.x, t = threadIdx.x;
    float x = W[i * 256 + t];
    float p1 = x * a[t];
    float p2 = x * a[256 + t];
#pragma unroll
    for (int off = 1; off < 64; off <<= 1) {
        p1 += __shfl_xor(p1, off);
        p2 += __shfl_xor(p2, off);
    }
    __shared__ float s1[4], s2[4];
    if ((t & 63) == 0) { s1[t >> 6] = p1; s2[t >> 6] = p2; }
    __syncthreads();
    if (t == 0) {
        w1[i] = s1[0] + s1[1] + s1[2] + s1[3];
        w2[i] = s2[0] + s2[1] + s2[2] + s2[3];
    }
    // transpose column i -> Wt row i, split hi/lo fp16
    float y = W[t * 256 + i];
    u16 hi = f2h(y);
    Wt_hi[i * 256 + t] = hi;
    Wt_lo[i * 256 + t] = f2h(y - h2f(hi));
}

// ---------------- per-batch max of f2 ---------------------------------------
__global__ void k_m(const float* __restrict__ f2, float* __restrict__ Mb) {
    int b = blockIdx.x, t = threadIdx.x;
    float m = -1e30f;
#pragma unroll
    for (int j = 0; j < 4; ++j) m = fmaxf(m, f2[b * 1024 + t + j * 256]);
#pragma unroll
    for (int off = 1; off < 64; off <<= 1) m = fmaxf(m, __shfl_xor(m, off));
    __shared__ float s[4];
    if ((t & 63) == 0) s[t >> 6] = m;
    __syncthreads();
    if (t == 0) Mb[b] = fmaxf(fmaxf(s[0], s[1]), fmaxf(s[2], s[3]));
}

// ---------------- k_h: ht = (inp @ W)^T fp16 (3-term split), + f1/f2 --------
// Block = 32 n-rows; 4 waves split f (64 each). Grid 1024 -> 4 blocks/CU.
__global__ __launch_bounds__(256, 4) void k_h(const float* __restrict__ inp,
                                              const u16* __restrict__ Wt_hi,
                                              const u16* __restrict__ Wt_lo,
                                              const float* __restrict__ w1,
                                              const float* __restrict__ w2,
                                              u16* __restrict__ ht,
                                              float* __restrict__ f1,
                                              float* __restrict__ f2) {
    __shared__ float sw1[256], sw2[256];
    int t = threadIdx.x, w = t >> 6, l = t & 63, lr = l & 15, lk = l >> 4;
    sw1[t] = w1[t];
    sw2[t] = w2[t];
    __syncthreads();
    int n0 = blockIdx.x * 32;
    int bb = n0 >> 10, nb0 = n0 & 1023;

    f32x4 acc[4][2];
#pragma unroll
    for (int i = 0; i < 4; ++i)
#pragma unroll
        for (int j = 0; j < 2; ++j)
#pragma unroll
            for (int r = 0; r < 4; ++r) acc[i][j][r] = 0.f;
    float d1[2] = {0.f, 0.f}, d2[2] = {0.f, 0.f};

    for (int kt = 0; kt < 8; ++kt) {
        int k0 = kt * 32 + lk * 8;
        f16x8 ah[4], al[4];
#pragma unroll
        for (int it = 0; it < 4; ++it) {
            int f = w * 64 + it * 16 + lr;
            ah[it] = *(const f16x8*)&Wt_hi[f * 256 + k0];
            al[it] = *(const f16x8*)&Wt_lo[f * 256 + k0];
        }
        f32x4 c1a = *(const f32x4*)&sw1[k0];
        f32x4 c1b = *(const f32x4*)&sw1[k0 + 4];
        f32x4 c2a = *(const f32x4*)&sw2[k0];
        f32x4 c2b = *(const f32x4*)&sw2[k0 + 4];
#pragma unroll
        for (int ci = 0; ci < 2; ++ci) {
            int n = n0 + ci * 16 + lr;
            f32x4 v0 = *(const f32x4*)&inp[n * 256 + k0];
            f32x4 v1 = *(const f32x4*)&inp[n * 256 + k0 + 4];
            d1[ci] += v0.x * c1a.x + v0.y * c1a.y + v0.z * c1a.z + v0.w * c1a.w +
                      v1.x * c1b.x + v1.y * c1b.y + v1.z * c1b.z + v1.w * c1b.w;
            d2[ci] += v0.x * c2a.x + v0.y * c2a.y + v0.z * c2a.z + v0.w * c2a.w +
                      v1.x * c2b.x + v1.y * c2b.y + v1.z * c2b.z + v1.w * c2b.w;
            u16x8 hv, lv;
#pragma unroll
            for (int j = 0; j < 4; ++j) {
                u16 h0 = f2h(v0[j]);
                hv[j] = h0;
                lv[j] = f2h(v0[j] - h2f(h0));
                u16 h1 = f2h(v1[j]);
                hv[j + 4] = h1;
                lv[j + 4] = f2h(v1[j] - h2f(h1));
            }
            f16x8 bh = *(f16x8*)&hv, bl = *(f16x8*)&lv;
#pragma unroll
            for (int it = 0; it < 4; ++it) {
                acc[it][ci] = __builtin_amdgcn_mfma_f32_16x16x32_f16(ah[it], bh, acc[it][ci], 0, 0, 0);
                acc[it][ci] = __builtin_amdgcn_mfma_f32_16x16x32_f16(ah[it], bl, acc[it][ci], 0, 0, 0);
                acc[it][ci] = __builtin_amdgcn_mfma_f32_16x16x32_f16(al[it], bh, acc[it][ci], 0, 0, 0);
            }
        }
    }
    // f1/f2: reduce over lk lanes; identical across waves -> wave 0 writes
#pragma unroll
    for (int ci = 0; ci < 2; ++ci) {
        d1[ci] += __shfl_xor(d1[ci], 16);
        d1[ci] += __shfl_xor(d1[ci], 32);
        d2[ci] += __shfl_xor(d2[ci], 16);
        d2[ci] += __shfl_xor(d2[ci], 32);
    }
    if (w == 0 && l < 16) {
#pragma unroll
        for (int ci = 0; ci < 2; ++ci) {
            f1[n0 + ci * 16 + l] = d1[ci];
            f2[n0 + ci * 16 + l] = d2[ci];
        }
    }
    // ht write (fp16)
#pragma unroll
    for (int it = 0; it < 4; ++it)
#pragma unroll
        for (int ci = 0; ci < 2; ++ci) {
            int col = nb0 + ci * 16 + lr;
#pragma unroll
            for (int r = 0; r < 4; ++r) {
                int F = w * 64 + it * 16 + lk * 4 + r;
                ht[(size_t)(bb * 256 + F) * 1024 + col] = f2h(acc[it][ci][r]);
            }
        }
}

// ---------------- attention: softmax(leaky(f1+f2)) @ h, elu -----------------
// 32-row tiles, 4 waves each owning a distinct 64-f slice (no H duplication).
// P (fp16) computed once, shared via double-buffered LDS; H read from L2.
__global__ __launch_bounds__(256, 4) void k_attn(const u16* __restrict__ ht,
                                                 const float* __restrict__ f1,
                                                 const float* __restrict__ f2,
                                                 const float* __restrict__ Mb,
                                                 float* __restrict__ out) {
    __shared__ float sf2[1024];
    __shared__ u16 P[2][2][4][512];  // [buf][rowgroup][s][lane*8]
    __shared__ float rs[64];
    int t = threadIdx.x, w = t >> 6, l = t & 63, lr = l & 15, lk = l >> 4;
    int g = blockIdx.x;
    int xcd = g & 7, idx = g >> 3;
    int b = xcd * 4 + (idx >> 5);
    int i0 = (idx & 31) * 32;

    *(f32x4*)&sf2[t * 4] = *(const f32x4*)&f2[b * 1024 + t * 4];
    float Mv = Mb[b];
    int rgp = w & 1;  // rowgroup this wave's P covers
    int jh = w >> 1;  // j-half this wave's P covers
    float f1v = f1[b * 1024 + i0 + rgp * 16 + lr];
    float miv = LRELU(f1v + Mv);
    float lsum = 0.f;
    const u16* H = ht + (size_t)b * 262144;

    auto computeP = [&](int cc2, int buf2) {
#pragma unroll
        for (int ss = 0; ss < 2; ++ss) {
            int s = jh * 2 + ss;
            int jb = cc2 * 128 + s * 32 + lk * 8;
            f32x4 fa = *(const f32x4*)&sf2[jb];
            f32x4 fb = *(const f32x4*)&sf2[jb + 4];
            u16x8 pv;
#pragma unroll
            for (int jj = 0; jj < 8; ++jj) {
                float fv = (jj < 4) ? fa[jj] : fb[jj - 4];
                float e = LRELU(f1v + fv);
                float p = __expf(e - miv);
                lsum += p;
                pv[jj] = f2h(p);
            }
            *(u16x8*)&P[buf2][rgp][s][l * 8] = pv;
        }
    };

    f32x4 acc[2][4];
#pragma unroll
    for (int i = 0; i < 2; ++i)
#pragma unroll
        for (int j = 0; j < 4; ++j)
#pragma unroll
            for (int r = 0; r < 4; ++r) acc[i][j][r] = 0.f;

    __syncthreads();  // sf2 visible
    computeP(0, 0);

    for (int cc = 0; cc < 8; ++cc) {
        __syncthreads();  // P(cc) visible; prev-buf readers done
        if (cc < 7) computeP(cc + 1, (cc + 1) & 1);
        int buf = cc & 1;
#pragma unroll
        for (int s = 0; s < 4; ++s) {
            int jcol = cc * 128 + s * 32 + lk * 8;
            f16x8 pf0 = *(const f16x8*)&P[buf][0][s][l * 8];
            f16x8 pf1 = *(const f16x8*)&P[buf][1][s][l * 8];
            __builtin_amdgcn_s_setprio(1);
#pragma unroll
            for (int ci = 0; ci < 4; ++ci) {
                int f = w * 64 + ci * 16 + lr;
                f16x8 bh = *(const f16x8*)&H[(size_t)f * 1024 + jcol];
                acc[0][ci] = __builtin_amdgcn_mfma_f32_16x16x32_f16(pf0, bh, acc[0][ci], 0, 0, 0);
                acc[1][ci] = __builtin_amdgcn_mfma_f32_16x16x32_f16(pf1, bh, acc[1][ci], 0, 0, 0);
            }
            __builtin_amdgcn_s_setprio(0);
        }
    }

    // row sums: reduce lk lanes in-wave, combine the two j-half waves per rg
    lsum += __shfl_xor(lsum, 16);
    lsum += __shfl_xor(lsum, 32);
    if (l < 16) rs[w * 16 + lr] = lsum;
    __syncthreads();

#pragma unroll
    for (int it = 0; it < 2; ++it) {
        f32x4 s1 = *(const f32x4*)&rs[it * 16 + lk * 4];
        f32x4 s2 = *(const f32x4*)&rs[(it + 2) * 16 + lk * 4];
        f32x4 sums = s1 + s2;
#pragma unroll
        for (int ci = 0; ci < 4; ++ci) {
            int col = w * 64 + ci * 16 + lr;
            int rowg = b * 1024 + i0 + it * 16 + lk * 4;
#pragma unroll
            for (int r = 0; r < 4; ++r) {
                float v = acc[it][ci][r] / sums[r];
                v = v > 0.f ? v : (__expf(v) - 1.f);
                out[(size_t)(rowg + r) * 256 + col] = v;
            }
        }
    }
}

extern "C" void kernel_launch(void* const* d_in, const int* in_sizes, int n_in,
                              void* d_out, int out_size, void* d_ws, size_t ws_size,
                              hipStream_t stream) {
    const float* inp = (const float*)d_in[0];
    const float* W = (const float*)d_in[1];
    const float* a = (const float*)d_in[2];
    float* out = (float*)d_out;

    char* ws = (char*)d_ws;
    u16* ht = (u16*)(ws + 0);               // 16,777,216 B (fp16)
    u16* Wt_hi = (u16*)(ws + 16777216);     // 131,072 B
    u16* Wt_lo = (u16*)(ws + 16908288);     // 131,072 B
    float* w1 = (float*)(ws + 17039360);    // 1,024 B
    float* w2 = (float*)(ws + 17040384);    // 1,024 B
    float* f1 = (float*)(ws + 17041408);    // 131,072 B
    float* f2 = (float*)(ws + 17172480);    // 131,072 B
    float* Mb = (float*)(ws + 17303552);    // 128 B

    k_prep<<<256, 256, 0, stream>>>(W, a, Wt_hi, Wt_lo, w1, w2);
    k_h<<<1024, 256, 0, stream>>>(inp, Wt_hi, Wt_lo, w1, w2, ht, f1, f2);
    k_m<<<32, 256, 0, stream>>>(f2, Mb);
    k_attn<<<1024, 256, 0, stream>>>(ht, f1, f2, Mb, out);
}